// Round 6
// baseline (37.215 us; speedup 1.0000x reference)
//
#include <hip/hip_runtime.h>

// CompressImageGPU: bilinear down(0.5, antialias) -> up -> +8x8 block noise -> clip,
// composed into one separable 6-tap conv on x.
// Round 6: TY=8 full-width tiles (LDS 28.7KB -> 4 blocks/CU, 100% occupancy,
// read/write phase overlap across blocks). 512 threads: 128 col-groups x 4 row
// slots; v-pass = 2 output rows/thread from 8-row window, all-constant indices.

typedef float f32x4 __attribute__((ext_vector_type(4)));

namespace {
constexpr int IMG = 512;
constexpr int TY = 8;           // output rows per block
constexpr int HROWS = TY + 6;   // 14
constexpr float I32 = 1.0f / 32.0f;
constexpr float I7  = 1.0f / 7.0f;
constexpr float I28 = 1.0f / 28.0f;
}

__device__ __forceinline__ f32x4 vfma(float w, f32x4 a, f32x4 acc) {
  acc.x = fmaf(w, a.x, acc.x); acc.y = fmaf(w, a.y, acc.y);
  acc.z = fmaf(w, a.z, acc.z); acc.w = fmaf(w, a.w, acc.w);
  return acc;
}
__device__ __forceinline__ f32x4 vmul(float w, f32x4 a) {
  f32x4 r; r.x = w * a.x; r.y = w * a.y; r.z = w * a.z; r.w = w * a.w;
  return r;
}

__global__ __launch_bounds__(512) void compress_fused6_kernel(
    const float* __restrict__ x, const float* __restrict__ bn,
    float* __restrict__ out) {
  // XCD-chunked bijective swizzle (nwg % 8 == 0): consecutive y-tiles of a
  // plane land on the same XCD so halo rows hit the same L2.
  const int nwg = gridDim.x;
  const int cpx = nwg >> 3;
  const int bid = blockIdx.x;
  const int logical = (bid & 7) * cpx + (bid >> 3);
  const int ty = logical & 63;      // y-tile 0..63
  const int plane = logical >> 6;   // 0..95
  const int b = plane / 3;
  const int y0 = ty * TY;
  const int tid = threadIdx.x;
  const int cg = tid & 127;         // column group: cols 4cg..4cg+3
  const int rs = tid >> 7;          // row slot 0..3 (uniform per wave)
  const int gx0 = 4 * cg;

  __shared__ float H[HROWS][IMG];   // 28.7 KB

  const float* xp = x + (size_t)plane * (IMG * IMG);
  float* op = out + (size_t)plane * (IMG * IMG);

  // per-thread noise value (one 8x8 block per 2 col-groups; whole tile = 1 block-row)
  const float nzv =
      (bn[(size_t)b * 4096 + (y0 >> 3) * 64 + (cg >> 1)] - 0.5f) * 0.02f;

  const bool left  = (cg == 0);
  const bool right = (cg == 127);
  const int A0 = left ? 0 : (right ? IMG - 12 : gx0 - 4);  // f[i] = x[A0+i]

  auto rowptr = [&](int r) -> const f32x4* {
    int g = y0 - 3 + r;
    g = max(0, min(IMG - 1, g));
    return (const f32x4*)(xp + (size_t)g * IMG + A0);
  };

  // ---- h-pass: rows rs, rs+4, rs+8, rs+12; 2-deep pipelined loads ----
  f32x4 qa, qb, qc;
  { const f32x4* p = rowptr(rs); qa = p[0]; qb = p[1]; qc = p[2]; }

#pragma unroll
  for (int k = 0; k < 4; ++k) {
    const int r = rs + 4 * k;
    const int rn = r + 4;
    f32x4 na, nb, nc;
    if (rn < HROWS) { const f32x4* p = rowptr(rn); na = p[0]; nb = p[1]; nc = p[2]; }
    if (r < HROWS) {
      const float f0 = qa.x, f1 = qa.y, f2 = qa.z, f3 = qa.w;
      const float f4_ = qb.x, f5 = qb.y, f6 = qb.z, f7 = qb.w;
      const float f8 = qc.x, f9 = qc.y, f10 = qc.z, f11 = qc.w;
      f32x4 h;
      if (left) {  // f[i] = x[i]
        h.x = (3.f * f0 + 3.f * f1 + f2) * I7;
        h.y = 9*I28*f0 + (9*I28 + I32)*f1 + (3*I28 + 3*I32)*f2 + 3*I32*f3 + I32*f4_;
        h.z = 3*I28*f0 + (3*I28 + 3*I32)*f1 + (I28 + 9*I32)*f2 + 9*I32*f3 + 3*I32*f4_;
        h.w = (3.f*f1 + 9.f*f2 + 10.f*f3 + 6.f*f4_ + 3.f*f5 + f6) * I32;
      } else if (right) {  // f[i] = x[500+i]
        h.x = (f5 + 3.f*f6 + 6.f*f7 + 10.f*f8 + 9.f*f9 + 3.f*f10) * I32;
        h.y = 3*I32*f7 + 9*I32*f8 + (I28 + 9*I32)*f9 + (3*I28 + 3*I32)*f10 + 3*I28*f11;
        h.z = I32*f7 + 3*I32*f8 + (3*I28 + 3*I32)*f9 + (9*I28 + I32)*f10 + 9*I28*f11;
        h.w = (f9 + 3.f*f10 + 3.f*f11) * I7;
      } else {  // f[i] = x[gx0-4+i]
        h.x = (f1 + 3.f*f2 + 6.f*f3 + 10.f*f4_ + 9.f*f5 + 3.f*f6) * I32;
        h.y = (3.f*f3 + 9.f*f4_ + 10.f*f5 + 6.f*f6 + 3.f*f7 + f8) * I32;
        h.z = (f3 + 3.f*f4_ + 6.f*f5 + 10.f*f6 + 9.f*f7 + 3.f*f8) * I32;
        h.w = (3.f*f5 + 9.f*f6 + 10.f*f7 + 6.f*f8 + 3.f*f9 + f10) * I32;
      }
      *(f32x4*)&H[r][gx0] = h;
    }
    if (rn < HROWS) { qa = na; qb = nb; qc = nc; }
  }
  __syncthreads();

  // ---- v-pass: 2 consecutive output rows (even,odd) from 8-row window ----
  const int wb = 2 * rs;  // H rows wb..wb+7; even row taps q0..q5, odd q2..q7
  const bool top = (y0 == 0);
  const bool bot = (y0 == IMG - TY);
  const int gy0 = y0 + 2 * rs;

#define LDQ(j) (*(const f32x4*)&H[wb + (j)][gx0])
  const f32x4 q0 = LDQ(0), q1 = LDQ(1), q2 = LDQ(2), q3 = LDQ(3);
  const f32x4 q4 = LDQ(4), q5 = LDQ(5), q6 = LDQ(6), q7 = LDQ(7);
#undef LDQ

  f32x4 oE, oO;
  if (top && rs == 0) {
    // gy=0: (3,3,1)/7 on x-rows 0,1,2 -> l=3,4,5 -> q3..q5
    oE = vfma(3*I7, q3, vfma(3*I7, q4, vmul(I7, q5)));
    // gy=1: rows 0..4 -> q3..q7
    oO = vfma(9*I28, q3, vfma(9*I28 + I32, q4,
         vfma(3*I28 + 3*I32, q5, vfma(3*I32, q6, vmul(I32, q7)))));
  } else if (top && rs == 1) {
    // gy=2: rows 0..4 -> l=3..7 -> q1..q5
    oE = vfma(3*I28, q1, vfma(3*I28 + 3*I32, q2,
         vfma(I28 + 9*I32, q3, vfma(9*I32, q4, vmul(3*I32, q5)))));
    // gy=3: interior odd
    oO = vfma(3*I32, q2, vfma(9*I32, q3, vfma(10*I32, q4,
         vfma(6*I32, q5, vfma(3*I32, q6, vmul(I32, q7))))));
  } else if (bot && rs == 2) {
    // gy=508: interior even
    oE = vfma(I32, q0, vfma(3*I32, q1, vfma(6*I32, q2,
         vfma(10*I32, q3, vfma(9*I32, q4, vmul(3*I32, q5))))));
    // gy=509: rows 507..511 -> l=6..10 -> q2..q6
    oO = vfma(3*I32, q2, vfma(9*I32, q3, vfma(I28 + 9*I32, q4,
         vfma(3*I28 + 3*I32, q5, vmul(3*I28, q6)))));
  } else if (bot && rs == 3) {
    // gy=510: rows 507..511 -> l=6..10 -> q0..q4
    oE = vfma(I32, q0, vfma(3*I32, q1, vfma(3*I28 + 3*I32, q2,
         vfma(9*I28 + I32, q3, vmul(9*I28, q4)))));
    // gy=511: rows 509,510,511 -> l=8,9,10 -> q2..q4
    oO = vfma(I7, q2, vfma(3*I7, q3, vmul(3*I7, q4)));
  } else {
    oE = vfma(I32, q0, vfma(3*I32, q1, vfma(6*I32, q2,
         vfma(10*I32, q3, vfma(9*I32, q4, vmul(3*I32, q5))))));
    oO = vfma(3*I32, q2, vfma(9*I32, q3, vfma(10*I32, q4,
         vfma(6*I32, q5, vfma(3*I32, q6, vmul(I32, q7))))));
  }

#define FINISH_STORE(o, ii)                                                    \
  {                                                                            \
    f32x4 v = o;                                                               \
    v.x = fminf(1.f, fmaxf(-1.f, v.x + nzv));                                  \
    v.y = fminf(1.f, fmaxf(-1.f, v.y + nzv));                                  \
    v.z = fminf(1.f, fmaxf(-1.f, v.z + nzv));                                  \
    v.w = fminf(1.f, fmaxf(-1.f, v.w + nzv));                                  \
    __builtin_nontemporal_store(v, (f32x4*)(op + (size_t)(gy0 + ii) * IMG + gx0)); \
  }
  FINISH_STORE(oE, 0)
  FINISH_STORE(oO, 1)
#undef FINISH_STORE
}

extern "C" void kernel_launch(void* const* d_in, const int* in_sizes, int n_in,
                              void* d_out, int out_size, void* d_ws, size_t ws_size,
                              hipStream_t stream) {
  const float* x  = (const float*)d_in[0];
  const float* bn = (const float*)d_in[1];
  float* out = (float*)d_out;

  const int n_planes = in_sizes[0] / (IMG * IMG);  // B*C = 96
  const int nwg = (IMG / TY) * n_planes;           // 64 * 96 = 6144 (div by 8)
  compress_fused6_kernel<<<dim3(nwg), dim3(512), 0, stream>>>(x, bn, out);
}